// Round 5
// baseline (215.594 us; speedup 1.0000x reference)
//
#include <hip/hip_runtime.h>
#include <hip/hip_fp16.h>

#define N_NODES 100000
#define N_EDGES 1600000
#define IN_C 64
#define HID_C 64
#define OUT_C 16

#define BKT 256        // nodes per dst bucket
#define BSH 8          // dst >> 8 = bucket
#define NBKT 391       // ceil(100000/256)
#define CAP 5120       // slots per bucket (mean 4092, +16 sigma margin)
#define GSTR 32        // gcnt stride in ints: one counter per 128B line
#define GB 512         // bin sub-blocks in merged pass 1
#define EPB 3125       // edges per bin block (512*3125 = 1.6M exact)
#define NIT 13         // ceil(EPB/256) register-cached edges per thread
#define G1B 1563       // gemm1 sub-blocks = ceil(100000/64)

typedef _Float16 f16x8 __attribute__((ext_vector_type(8)));
typedef float f32x4 __attribute__((ext_vector_type(4)));
typedef float f32x16 __attribute__((ext_vector_type(16)));

// ---------------------------------------------------------------------------
// Merged pass 1 (round-0 best config): blocks [0,GB) bin edges; blocks
// [GB, GB+G1B) do GEMM1 (MFMA). Bin: dst/src register-cached (one global read
// pass), LDS bucket histogram -> one global atomicAdd per (block,bucket)
// reserves bucket range -> scatter. gcnt line-padded (GSTR).
// ---------------------------------------------------------------------------
__global__ __launch_bounds__(256) void k_merged1(
    const int* __restrict__ src, const int* __restrict__ dst,
    int* __restrict__ gcnt, int* __restrict__ binned,
    const float* __restrict__ x, const float* __restrict__ Wl,
    const float* __restrict__ Wr, const float* __restrict__ b,
    __half* __restrict__ p, __half* __restrict__ q) {
  __shared__ _Float16 sA[64 * 68];    // gemm: [row][k]   | bin: h[] alias
  __shared__ _Float16 sW[128 * 68];   // gemm: [col][k]^T | bin: cur[] alias
  int t = threadIdx.x;

  if (blockIdx.x < GB) {
    int* h   = (int*)sA;              // NBKT ints
    int* cur = (int*)sW;              // NBKT ints
    for (int i = t; i < NBKT; i += 256) h[i] = 0;
    __syncthreads();
    int base = blockIdx.x * EPB;
    int end = base + EPB;
    int dv[NIT], sv[NIT];
#pragma unroll
    for (int it = 0; it < NIT; ++it) {
      int e = base + t + it * 256;
      bool ok = (e < end);
      dv[it] = ok ? dst[e] : -1;
      sv[it] = ok ? src[e] : 0;
    }
#pragma unroll
    for (int it = 0; it < NIT; ++it)
      if (dv[it] >= 0) atomicAdd(&h[dv[it] >> BSH], 1);
    __syncthreads();
    for (int i = t; i < NBKT; i += 256) {
      int c = h[i];
      int b0 = (c > 0) ? atomicAdd(&gcnt[i * GSTR], c) : 0;  // reserve range
      cur[i] = i * CAP + b0;
    }
    __syncthreads();
#pragma unroll
    for (int it = 0; it < NIT; ++it) {
      if (dv[it] >= 0) {
        int d = dv[it];
        int pos = atomicAdd(&cur[d >> BSH], 1);
        binned[pos] = (sv[it] << BSH) | (d & (BKT - 1));
      }
    }
    return;
  }

  // ---------------- gemm1 body ----------------
  int n0 = (blockIdx.x - GB) * 64;

  for (int f = t; f < 1024; f += 256) {
    int r = f >> 4, c4 = f & 15;
    int n = n0 + r;
    float4 v = {0.0f, 0.0f, 0.0f, 0.0f};
    if (n < N_NODES) v = *(const float4*)&x[(size_t)n * 64 + c4 * 4];
    union { _Float16 h[4]; float2 f2; } u;
    u.h[0] = (_Float16)v.x; u.h[1] = (_Float16)v.y;
    u.h[2] = (_Float16)v.z; u.h[3] = (_Float16)v.w;
    *(float2*)&sA[r * 68 + c4 * 4] = u.f2;
  }
  for (int f = t; f < 2048; f += 256) {
    int k = f >> 5, c4 = f & 31;
    float4 w = (c4 < 16) ? *(const float4*)&Wl[k * 64 + c4 * 4]
                         : *(const float4*)&Wr[k * 64 + (c4 - 16) * 4];
    int c = c4 * 4;
    sW[(c + 0) * 68 + k] = (_Float16)w.x;
    sW[(c + 1) * 68 + k] = (_Float16)w.y;
    sW[(c + 2) * 68 + k] = (_Float16)w.z;
    sW[(c + 3) * 68 + k] = (_Float16)w.w;
  }
  __syncthreads();

  int w = t >> 6, lane = t & 63;
  int m = lane & 31, half = lane >> 5;
  int rt = w & 1, cg2 = w >> 1;

  f32x16 acc[2];
#pragma unroll
  for (int r = 0; r < 16; ++r) { acc[0][r] = 0.0f; acc[1][r] = 0.0f; }

  const _Float16* pA = &sA[(rt * 32 + m) * 68 + half * 8];
  const _Float16* pB0 = &sW[(cg2 * 64 + m) * 68 + half * 8];
  const _Float16* pB1 = &sW[(cg2 * 64 + 32 + m) * 68 + half * 8];
#pragma unroll
  for (int kc = 0; kc < 4; ++kc) {
    union { f16x8 v; float2 f2[2]; } a, b0, b1;
    a.f2[0] = *(const float2*)(pA + kc * 16);
    a.f2[1] = *(const float2*)(pA + kc * 16 + 4);
    b0.f2[0] = *(const float2*)(pB0 + kc * 16);
    b0.f2[1] = *(const float2*)(pB0 + kc * 16 + 4);
    b1.f2[0] = *(const float2*)(pB1 + kc * 16);
    b1.f2[1] = *(const float2*)(pB1 + kc * 16 + 4);
    acc[0] = __builtin_amdgcn_mfma_f32_32x32x16_f16(a.v, b0.v, acc[0], 0, 0, 0);
    acc[1] = __builtin_amdgcn_mfma_f32_32x32x16_f16(a.v, b1.v, acc[1], 0, 0, 0);
  }

  if (cg2 == 0) {
#pragma unroll
    for (int tt = 0; tt < 2; ++tt) {
      int col = tt * 32 + m;
#pragma unroll
      for (int r = 0; r < 16; ++r) {
        int row = (r & 3) + 4 * half + 8 * (r >> 2);
        int n = n0 + rt * 32 + row;
        if (n < N_NODES) p[(size_t)n * 64 + col] = __float2half(acc[tt][r]);
      }
    }
  } else {
    float bias[2] = {b[m], b[32 + m]};
#pragma unroll
    for (int tt = 0; tt < 2; ++tt) {
      int col = tt * 32 + m;
#pragma unroll
      for (int r = 0; r < 16; ++r) {
        int row = (r & 3) + 4 * half + 8 * (r >> 2);
        int n = n0 + rt * 32 + row;
        if (n < N_NODES)
          q[(size_t)n * 64 + col] = __float2half(acc[tt][r] + bias[tt]);
      }
    }
  }
}

// ---------------------------------------------------------------------------
// Fuse12: finalize ∪ fuse1 ∪ gemm2 ∪ device barrier ∪ fuse2 — plain launch,
// 512 thr/block, __launch_bounds__(512,4): VGPR<=128, 8 waves/block ->
// GUARANTEED 2 blocks/CU (threads 1024/CU, LDS 2x62.7KB<=160KB, VGPR
// 4 waves/EU). 391 blocks <= 512 resident slots -> barrier cannot deadlock;
// spin is bounded anyway (fail-soft).
// Phase A: reg-cached binned (10/thr) -> LDS histogram -> wave shfl scan ->
//          scatter into LDS lcsr. No csr/rowstart/cnt export.
// Phase B: h = relu(mean_j p1[lcsr_j] + q1) -> fp16 LDS sH (64 grp x 4 rows).
// Phase C: 8 waves x 2 MFMA tiles; cols 0-15 -> p2 (global), 16-31 kept in
//          regs then -> q2l LDS (aliases sH after barrier).
// Barrier: syncthreads -> t0: threadfence / atomicAdd / spin / threadfence ->
//          syncthreads.
// Phase D: out[n] = mean_j p2[lcsr_j] + q2l[n]; 2 thr/node, av[8] unroll.
// ---------------------------------------------------------------------------
__global__ __launch_bounds__(512, 4) void k_fuse12(
    const float4* __restrict__ p1, const int* __restrict__ gcnt,
    const int* __restrict__ binned, const float* __restrict__ W2l,
    const float* __restrict__ W2r, const float* __restrict__ b2,
    const float4* __restrict__ q1, __half* __restrict__ p2,
    int* __restrict__ bar, float4* __restrict__ out) {
  __shared__ int hcnt[BKT];
  __shared__ int hscan[BKT];
  __shared__ int cur[BKT];
  __shared__ int lcsr[CAP];          // 20 KB
  __shared__ _Float16 sH[256 * 68];  // 34 KB; aliased as q2l f32[256*16] in D
  __shared__ _Float16 sW[32 * 68];   // 4.25 KB [col][k]^T: 0-15 W2l, 16-31 W2r
  int b = blockIdx.x;
  int t = threadIdx.x;

  {  // stage W2^T (512 half4 chunks, one per thread)
    int k = t >> 3, c4v = t & 7;
    float4 w = (c4v < 4) ? *(const float4*)&W2l[k * 16 + c4v * 4]
                         : *(const float4*)&W2r[k * 16 + (c4v - 4) * 4];
    int c = c4v * 4;
    sW[(c + 0) * 68 + k] = (_Float16)w.x;
    sW[(c + 1) * 68 + k] = (_Float16)w.y;
    sW[(c + 2) * 68 + k] = (_Float16)w.z;
    sW[(c + 3) * 68 + k] = (_Float16)w.w;
  }
  if (t < BKT) hcnt[t] = 0;
  __syncthreads();

  // ---- Phase A ----
  int start = b * CAP;
  int total = gcnt[b * GSTR];
  int ev[10];
#pragma unroll
  for (int u = 0; u < 10; ++u) {      // one global read pass, reg-cached
    int i = t + u * 512;
    ev[u] = (i < total) ? binned[start + i] : -1;
  }
#pragma unroll
  for (int u = 0; u < 10; ++u)
    if (ev[u] >= 0) atomicAdd(&hcnt[ev[u] & (BKT - 1)], 1);
  __syncthreads();
  if (t < 64) {  // single-wave inclusive scan of 256 counters (4 segments)
    int s0 = hcnt[t], s1 = hcnt[64 + t], s2 = hcnt[128 + t], s3 = hcnt[192 + t];
    for (int st = 1; st < 64; st <<= 1) {
      int a0 = __shfl_up(s0, st), a1 = __shfl_up(s1, st);
      int a2 = __shfl_up(s2, st), a3 = __shfl_up(s3, st);
      if (t >= st) { s0 += a0; s1 += a1; s2 += a2; s3 += a3; }
    }
    int t0 = __shfl(s0, 63), t1 = __shfl(s1, 63), t2 = __shfl(s2, 63);
    hscan[t] = s0;
    hscan[64 + t] = s1 + t0;
    hscan[128 + t] = s2 + t0 + t1;
    hscan[192 + t] = s3 + t0 + t1 + t2;
  }
  __syncthreads();
  if (t < BKT) cur[t] = hscan[t] - hcnt[t];  // local exclusive start
  __syncthreads();
#pragma unroll
  for (int u = 0; u < 10; ++u) {
    if (ev[u] >= 0) {
      int vv = ev[u];
      int pos = atomicAdd(&cur[vv & (BKT - 1)], 1);
      lcsr[pos] = vv >> BSH;
    }
  }
  __syncthreads();

  // ---- Phase B: aggregate + relu -> sH (fp16); 64 groups x 4 rows ----
  int g = t >> 3, c4 = t & 7;
  for (int r = g; r < BKT; r += 64) {
    int n = (b << BSH) + r;
    if (n < N_NODES) {
      int deg = hcnt[r];
      int row = hscan[r] - deg;  // local start in lcsr
      float acc[8];
#pragma unroll
      for (int m = 0; m < 8; ++m) acc[m] = 0.0f;
      int j = 0;
      for (; j + 8 <= deg; j += 8) {
        int idx[8];
#pragma unroll
        for (int u = 0; u < 8; ++u) idx[u] = lcsr[row + j + u];
        float4 av[8];
#pragma unroll
        for (int u = 0; u < 8; ++u) av[u] = p1[idx[u] * 8 + c4];
#pragma unroll
        for (int u = 0; u < 8; ++u) {
          const __half2* h = (const __half2*)&av[u];
#pragma unroll
          for (int m = 0; m < 4; ++m) {
            float2 f = __half22float2(h[m]);
            acc[2 * m] += f.x;
            acc[2 * m + 1] += f.y;
          }
        }
      }
      for (; j < deg; ++j) {
        float4 a = p1[lcsr[row + j] * 8 + c4];
        const __half2* h = (const __half2*)&a;
#pragma unroll
        for (int m = 0; m < 4; ++m) {
          float2 f = __half22float2(h[m]);
          acc[2 * m] += f.x;
          acc[2 * m + 1] += f.y;
        }
      }
      float inv = 1.0f / fmaxf((float)deg, 1.0f);
      float4 qv = q1[n * 8 + c4];
      __half2* qh = (__half2*)&qv;
      union { __half2 h2[2]; float2 f2; } u01, u23;
#pragma unroll
      for (int m = 0; m < 2; ++m) {
        float2 f = __half22float2(qh[m]);
        float2 s;
        s.x = fmaxf(acc[2 * m] * inv + f.x, 0.0f);
        s.y = fmaxf(acc[2 * m + 1] * inv + f.y, 0.0f);
        u01.h2[m] = __float22half2_rn(s);
      }
#pragma unroll
      for (int m = 2; m < 4; ++m) {
        float2 f = __half22float2(qh[m]);
        float2 s;
        s.x = fmaxf(acc[2 * m] * inv + f.x, 0.0f);
        s.y = fmaxf(acc[2 * m + 1] * inv + f.y, 0.0f);
        u23.h2[m - 2] = __float22half2_rn(s);
      }
      *(float2*)&sH[r * 68 + c4 * 8] = u01.f2;
      *(float2*)&sH[r * 68 + c4 * 8 + 4] = u23.f2;
    } else {
      // zero pad rows beyond N_NODES so phase C MFMA reads defined data
      *(float2*)&sH[r * 68 + c4 * 8] = make_float2(0.0f, 0.0f);
      *(float2*)&sH[r * 68 + c4 * 8 + 4] = make_float2(0.0f, 0.0f);
    }
  }
  __syncthreads();

  // ---- Phase C: 8 waves x 2 tiles of 16 rows each ----
  int wv = t >> 6, lane = t & 63;
  int n16 = lane & 15, quad = lane >> 4;
  float bias = b2[n16];
  float q2v[2][4];
#pragma unroll
  for (int h2 = 0; h2 < 2; ++h2) {
    int tile = wv + h2 * 8;
    f32x4 aP, aQ;
#pragma unroll
    for (int r = 0; r < 4; ++r) { aP[r] = 0.0f; aQ[r] = 0.0f; }
    const _Float16* pA = &sH[(tile * 16 + n16) * 68 + quad * 8];
    const _Float16* pBP = &sW[n16 * 68 + quad * 8];
    const _Float16* pBQ = &sW[(16 + n16) * 68 + quad * 8];
#pragma unroll
    for (int kc = 0; kc < 2; ++kc) {
      union { f16x8 v; float2 f2[2]; } a, bp, bq;
      a.f2[0] = *(const float2*)(pA + kc * 32);
      a.f2[1] = *(const float2*)(pA + kc * 32 + 4);
      bp.f2[0] = *(const float2*)(pBP + kc * 32);
      bp.f2[1] = *(const float2*)(pBP + kc * 32 + 4);
      bq.f2[0] = *(const float2*)(pBQ + kc * 32);
      bq.f2[1] = *(const float2*)(pBQ + kc * 32 + 4);
      aP = __builtin_amdgcn_mfma_f32_16x16x32_f16(a.v, bp.v, aP, 0, 0, 0);
      aQ = __builtin_amdgcn_mfma_f32_16x16x32_f16(a.v, bq.v, aQ, 0, 0, 0);
    }
#pragma unroll
    for (int r = 0; r < 4; ++r) {   // p2 -> global (needed cross-block)
      int row = tile * 16 + quad * 4 + r;
      int n = (b << BSH) + row;
      if (n < N_NODES) p2[(size_t)n * 16 + n16] = __float2half(aP[r]);
      q2v[h2][r] = aQ[r] + bias;
    }
  }
  __syncthreads();               // all sH reads done -> safe to alias as q2l
  float* q2l = (float*)sH;       // [256][16] f32 = 16 KB
#pragma unroll
  for (int h2 = 0; h2 < 2; ++h2) {
#pragma unroll
    for (int r = 0; r < 4; ++r) {
      int row = (wv + h2 * 8) * 16 + quad * 4 + r;
      q2l[row * 16 + n16] = q2v[h2][r];
    }
  }

  // ---- device-wide barrier (2 blocks/CU guaranteed; 391 <= 512 slots) ----
  __syncthreads();               // drains this block's p2 stores (vmcnt)
  if (t == 0) {
    __threadfence();             // release: write back XCD L2
    atomicAdd(bar, 1);           // device-scope
    int spins = 0;
    while (__hip_atomic_load(bar, __ATOMIC_RELAXED,
                             __HIP_MEMORY_SCOPE_AGENT) < NBKT) {
      __builtin_amdgcn_s_sleep(2);
      if (++spins > 10000000) break;  // fail-soft: never hang
    }
    __threadfence();             // acquire: invalidate stale L1/L2 lines
  }
  __syncthreads();

  // ---- Phase D: out[n] = mean_j p2[lcsr_j] + q2l[n]; 2 thr/node ----
  {
    int r = t >> 1, c8 = t & 1;
    int n = (b << BSH) + r;
    if (n < N_NODES) {
      int deg = hcnt[r];
      int row0 = hscan[r] - deg;
      float acc[8];
#pragma unroll
      for (int m = 0; m < 8; ++m) acc[m] = 0.0f;
      const float4* p2v = (const float4*)p2;
      int j = 0;
      for (; j + 8 <= deg; j += 8) {
        int idx[8];
#pragma unroll
        for (int u = 0; u < 8; ++u) idx[u] = lcsr[row0 + j + u];
        float4 av[8];
#pragma unroll
        for (int u = 0; u < 8; ++u) av[u] = p2v[idx[u] * 2 + c8];
#pragma unroll
        for (int u = 0; u < 8; ++u) {
          const __half2* h = (const __half2*)&av[u];
#pragma unroll
          for (int m = 0; m < 4; ++m) {
            float2 f = __half22float2(h[m]);
            acc[2 * m] += f.x;
            acc[2 * m + 1] += f.y;
          }
        }
      }
      for (; j < deg; ++j) {
        float4 a = p2v[lcsr[row0 + j] * 2 + c8];
        const __half2* h = (const __half2*)&a;
#pragma unroll
        for (int m = 0; m < 4; ++m) {
          float2 f = __half22float2(h[m]);
          acc[2 * m] += f.x;
          acc[2 * m + 1] += f.y;
        }
      }
      float inv = 1.0f / fmaxf((float)deg, 1.0f);
      const float* qr = &q2l[r * 16 + c8 * 8];
      float4 o0 = {acc[0] * inv + qr[0], acc[1] * inv + qr[1],
                   acc[2] * inv + qr[2], acc[3] * inv + qr[3]};
      float4 o1 = {acc[4] * inv + qr[4], acc[5] * inv + qr[5],
                   acc[6] * inv + qr[6], acc[7] * inv + qr[7]};
      out[n * 4 + c8 * 2] = o0;
      out[n * 4 + c8 * 2 + 1] = o1;
    }
  }
}

extern "C" void kernel_launch(void* const* d_in, const int* in_sizes, int n_in,
                              void* d_out, int out_size, void* d_ws, size_t ws_size,
                              hipStream_t stream) {
  const float* x   = (const float*)d_in[0];
  const int* edge  = (const int*)d_in[1];
  const int* src   = edge;            // edge_index[0]
  const int* dst   = edge + N_EDGES;  // edge_index[1]
  const float* W1l = (const float*)d_in[2];
  const float* b1  = (const float*)d_in[3];
  const float* W1r = (const float*)d_in[4];
  const float* W2l = (const float*)d_in[5];
  const float* b2  = (const float*)d_in[6];
  const float* W2r = (const float*)d_in[7];
  float* out = (float*)d_out;

  // workspace layout (4-byte units; fp16 bases 16B aligned)
  int* gcnt     = (int*)d_ws;          // NBKT*GSTR = 12512; bar at +12512
  int* bar      = gcnt + 12512;        // device-wide barrier counter
  int* binned   = gcnt + 12544;        // NBKT*CAP = 2001920
  __half* p1    = (__half*)(binned + NBKT * CAP);  // 6.4M halves (12.8 MB)
  __half* q1    = p1 + (size_t)N_NODES * 64;       // 6.4M halves (12.8 MB)
  __half* p2    = q1 + (size_t)N_NODES * 64;       // 1.6M halves (3.2 MB)

  hipMemsetAsync(gcnt, 0, 12544 * sizeof(int), stream);  // gcnt + bar

  // 1: bin ∪ gemm1 (independent, one dispatch; bin blocks first)
  k_merged1<<<GB + G1B, 256, 0, stream>>>(src, dst, gcnt, binned,
                                          x, W1l, W1r, b1, p1, q1);
  // 2: fused fuse1+gemm2+barrier+fuse2 (391 blocks x 512 thr, 2 blocks/CU)
  k_fuse12<<<NBKT, 512, 0, stream>>>((const float4*)p1, gcnt, binned,
                                     W2l, W2r, b2, (const float4*)q1,
                                     p2, bar, (float4*)out);
}

// Round 6
// 184.151 us; speedup vs baseline: 1.1707x; 1.1707x over previous
//
#include <hip/hip_runtime.h>
#include <hip/hip_fp16.h>

#define N_NODES 100000
#define N_EDGES 1600000
#define IN_C 64
#define HID_C 64
#define OUT_C 16

#define BKT 256        // nodes per dst bucket
#define BSH 8          // dst >> 8 = bucket
#define NBKT 391       // ceil(100000/256)
#define CAP 5120       // slots per bucket (mean 4092, +16 sigma margin)
#define GSTR 32        // gcnt stride in ints: one counter per 128B line
#define GB 512         // bin sub-blocks in merged pass 1
#define EPB 3125       // edges per bin block (512*3125 = 1.6M exact)
#define NIT 13         // ceil(EPB/256) register-cached edges per thread
#define G1B 1563       // gemm1 sub-blocks = ceil(100000/64)

typedef _Float16 f16x8 __attribute__((ext_vector_type(8)));
typedef float f32x4 __attribute__((ext_vector_type(4)));
typedef float f32x16 __attribute__((ext_vector_type(16)));

// ---------------------------------------------------------------------------
// Merged pass 1: blocks [0,GB) bin edges; blocks [GB, GB+G1B) do GEMM1 (MFMA).
// Bin: dst/src register-cached (one global read pass), 4-way split LDS bucket
// histogram (cuts same-address atomic serialization ~4x) -> one global
// atomicAdd per (block,bucket) reserves bucket range -> scatter (single cur:
// keeps per-bucket runs contiguous; splitting cur re-fragments writes).
// ---------------------------------------------------------------------------
__global__ __launch_bounds__(256) void k_merged1(
    const int* __restrict__ src, const int* __restrict__ dst,
    int* __restrict__ gcnt, int* __restrict__ binned,
    const float* __restrict__ x, const float* __restrict__ Wl,
    const float* __restrict__ Wr, const float* __restrict__ b,
    __half* __restrict__ p, __half* __restrict__ q) {
  __shared__ _Float16 sA[64 * 68];    // gemm: [row][k]   | bin: h4[] alias
  __shared__ _Float16 sW[128 * 68];   // gemm: [col][k]^T | bin: cur[] alias
  int t = threadIdx.x;

  if (blockIdx.x < GB) {
    int* h4  = (int*)sA;              // 4*NBKT = 1564 ints (6256B <= 8704B)
    int* cur = (int*)sW;              // NBKT ints
    for (int i = t; i < 4 * NBKT; i += 256) h4[i] = 0;
    __syncthreads();
    int base = blockIdx.x * EPB;
    int end = base + EPB;
    int dv[NIT], sv[NIT];
#pragma unroll
    for (int it = 0; it < NIT; ++it) {
      int e = base + t + it * 256;
      bool ok = (e < end);
      dv[it] = ok ? dst[e] : -1;
      sv[it] = ok ? src[e] : 0;
    }
    int hoff = (t & 3) * NBKT;        // 4-way copy split by lane%4
#pragma unroll
    for (int it = 0; it < NIT; ++it)
      if (dv[it] >= 0) atomicAdd(&h4[hoff + (dv[it] >> BSH)], 1);
    __syncthreads();
    for (int i = t; i < NBKT; i += 256) {
      int c = h4[i] + h4[NBKT + i] + h4[2 * NBKT + i] + h4[3 * NBKT + i];
      int b0 = (c > 0) ? atomicAdd(&gcnt[i * GSTR], c) : 0;  // reserve range
      cur[i] = i * CAP + b0;
    }
    __syncthreads();
#pragma unroll
    for (int it = 0; it < NIT; ++it) {
      if (dv[it] >= 0) {
        int d = dv[it];
        int pos = atomicAdd(&cur[d >> BSH], 1);
        binned[pos] = (sv[it] << BSH) | (d & (BKT - 1));
      }
    }
    return;
  }

  // ---------------- gemm1 body ----------------
  int n0 = (blockIdx.x - GB) * 64;

  for (int f = t; f < 1024; f += 256) {
    int r = f >> 4, c4 = f & 15;
    int n = n0 + r;
    float4 v = {0.0f, 0.0f, 0.0f, 0.0f};
    if (n < N_NODES) v = *(const float4*)&x[(size_t)n * 64 + c4 * 4];
    union { _Float16 h[4]; float2 f2; } u;
    u.h[0] = (_Float16)v.x; u.h[1] = (_Float16)v.y;
    u.h[2] = (_Float16)v.z; u.h[3] = (_Float16)v.w;
    *(float2*)&sA[r * 68 + c4 * 4] = u.f2;
  }
  for (int f = t; f < 2048; f += 256) {
    int k = f >> 5, c4 = f & 31;
    float4 w = (c4 < 16) ? *(const float4*)&Wl[k * 64 + c4 * 4]
                         : *(const float4*)&Wr[k * 64 + (c4 - 16) * 4];
    int c = c4 * 4;
    sW[(c + 0) * 68 + k] = (_Float16)w.x;
    sW[(c + 1) * 68 + k] = (_Float16)w.y;
    sW[(c + 2) * 68 + k] = (_Float16)w.z;
    sW[(c + 3) * 68 + k] = (_Float16)w.w;
  }
  __syncthreads();

  int w = t >> 6, lane = t & 63;
  int m = lane & 31, half = lane >> 5;
  int rt = w & 1, cg = w >> 1;

  f32x16 acc[2];
#pragma unroll
  for (int r = 0; r < 16; ++r) { acc[0][r] = 0.0f; acc[1][r] = 0.0f; }

  const _Float16* pA = &sA[(rt * 32 + m) * 68 + half * 8];
  const _Float16* pB0 = &sW[(cg * 64 + m) * 68 + half * 8];
  const _Float16* pB1 = &sW[(cg * 64 + 32 + m) * 68 + half * 8];
#pragma unroll
  for (int kc = 0; kc < 4; ++kc) {
    union { f16x8 v; float2 f2[2]; } a, b0, b1;
    a.f2[0] = *(const float2*)(pA + kc * 16);
    a.f2[1] = *(const float2*)(pA + kc * 16 + 4);
    b0.f2[0] = *(const float2*)(pB0 + kc * 16);
    b0.f2[1] = *(const float2*)(pB0 + kc * 16 + 4);
    b1.f2[0] = *(const float2*)(pB1 + kc * 16);
    b1.f2[1] = *(const float2*)(pB1 + kc * 16 + 4);
    acc[0] = __builtin_amdgcn_mfma_f32_32x32x16_f16(a.v, b0.v, acc[0], 0, 0, 0);
    acc[1] = __builtin_amdgcn_mfma_f32_32x32x16_f16(a.v, b1.v, acc[1], 0, 0, 0);
  }

  if (cg == 0) {
#pragma unroll
    for (int tt = 0; tt < 2; ++tt) {
      int col = tt * 32 + m;
#pragma unroll
      for (int r = 0; r < 16; ++r) {
        int row = (r & 3) + 4 * half + 8 * (r >> 2);
        int n = n0 + rt * 32 + row;
        if (n < N_NODES) p[(size_t)n * 64 + col] = __float2half(acc[tt][r]);
      }
    }
  } else {
    float bias[2] = {b[m], b[32 + m]};
#pragma unroll
    for (int tt = 0; tt < 2; ++tt) {
      int col = tt * 32 + m;
#pragma unroll
      for (int r = 0; r < 16; ++r) {
        int row = (r & 3) + 4 * half + 8 * (r >> 2);
        int n = n0 + rt * 32 + row;
        if (n < N_NODES)
          q[(size_t)n * 64 + col] = __float2half(acc[tt][r] + bias[tt]);
      }
    }
  }
}

// ---------------------------------------------------------------------------
// Fuse1c (finalize ∪ fuse1 ∪ gemm2): one block per 256-node bucket, 1024 thr.
// Phase A: reg-cached binned (ev[5], one global read) -> LDS histogram ->
//          single-wave shfl scan -> scatter into LDS lcsr; export
//          csr/rowstart/cnt for fuse2.
// Phase B: h = relu(mean_j p1[lcsr_j] + q1) -> fp16 LDS sH (128 groups x
//          2 nodes, 8 lanes x float4); zero-pad tail rows.
// Phase C: MFMA 256x32 K=64: 16 waves x one 16-row tile,
//          mfma_f32_16x16x32_f16; cols 0-15 -> p2, 16-31 -> q2+bias.
// ---------------------------------------------------------------------------
__global__ __launch_bounds__(1024) void k_fuse1c(
    const float4* __restrict__ p1, const int* __restrict__ gcnt,
    const int* __restrict__ binned, const float* __restrict__ W2l,
    const float* __restrict__ W2r, const float* __restrict__ b2,
    const float4* __restrict__ q1, int* __restrict__ csr,
    int* __restrict__ rowstart, int* __restrict__ cnt,
    __half* __restrict__ p2, float* __restrict__ q2) {
  __shared__ int hcnt[BKT];
  __shared__ int hscan[BKT];
  __shared__ int cur[BKT];
  __shared__ int lcsr[CAP];          // 20 KB
  __shared__ _Float16 sH[256 * 68];  // 34.8 KB
  __shared__ _Float16 sW[32 * 68];   // 4.4 KB [col][k]^T: 0-15 W2l, 16-31 W2r
  int b = blockIdx.x;
  int t = threadIdx.x;

  if (t < 512) {  // stage W2^T (512 half4 chunks)
    int k = t >> 3, c4v = t & 7;
    float4 w = (c4v < 4) ? *(const float4*)&W2l[k * 16 + c4v * 4]
                         : *(const float4*)&W2r[k * 16 + (c4v - 4) * 4];
    int c = c4v * 4;
    sW[(c + 0) * 68 + k] = (_Float16)w.x;
    sW[(c + 1) * 68 + k] = (_Float16)w.y;
    sW[(c + 2) * 68 + k] = (_Float16)w.z;
    sW[(c + 3) * 68 + k] = (_Float16)w.w;
  }
  if (t < BKT) hcnt[t] = 0;
  __syncthreads();

  // ---- Phase A ----
  int start = b * CAP;
  int total = gcnt[b * GSTR];
  int ev[5];
#pragma unroll
  for (int u = 0; u < 5; ++u) {       // one global read pass, reg-cached
    int i = t + u * 1024;
    ev[u] = (i < total) ? binned[start + i] : -1;
  }
#pragma unroll
  for (int u = 0; u < 5; ++u)
    if (ev[u] >= 0) atomicAdd(&hcnt[ev[u] & (BKT - 1)], 1);
  __syncthreads();
  if (t < 64) {  // single-wave inclusive scan of 256 counters (4 segments)
    int s0 = hcnt[t], s1 = hcnt[64 + t], s2 = hcnt[128 + t], s3 = hcnt[192 + t];
    for (int st = 1; st < 64; st <<= 1) {
      int a0 = __shfl_up(s0, st), a1 = __shfl_up(s1, st);
      int a2 = __shfl_up(s2, st), a3 = __shfl_up(s3, st);
      if (t >= st) { s0 += a0; s1 += a1; s2 += a2; s3 += a3; }
    }
    int t0 = __shfl(s0, 63), t1 = __shfl(s1, 63), t2 = __shfl(s2, 63);
    hscan[t] = s0;
    hscan[64 + t] = s1 + t0;
    hscan[128 + t] = s2 + t0 + t1;
    hscan[192 + t] = s3 + t0 + t1 + t2;
  }
  __syncthreads();
  if (t < BKT) {
    int v = hcnt[t];
    int e0 = hscan[t] - v;          // local exclusive start
    cur[t] = e0;
    int n = (b << BSH) + t;
    if (n < N_NODES) {
      rowstart[n] = start + e0;
      cnt[n] = v;
    }
  }
  __syncthreads();
#pragma unroll
  for (int u = 0; u < 5; ++u) {
    if (ev[u] >= 0) {
      int vv = ev[u];
      int pos = atomicAdd(&cur[vv & (BKT - 1)], 1);
      lcsr[pos] = vv >> BSH;
    }
  }
  __syncthreads();
  for (int i = t; i < total; i += 1024) csr[start + i] = lcsr[i];  // for fuse2

  // ---- Phase B: aggregate + relu -> sH (fp16); 128 groups x 2 nodes ----
  int g = t >> 3, c4 = t & 7;
  for (int r = g; r < BKT; r += 128) {
    int n = (b << BSH) + r;
    if (n < N_NODES) {
      int deg = hcnt[r];
      int row = hscan[r] - deg;  // local start in lcsr
      float acc[8];
#pragma unroll
      for (int m = 0; m < 8; ++m) acc[m] = 0.0f;
      int j = 0;
      for (; j + 8 <= deg; j += 8) {
        int idx[8];
#pragma unroll
        for (int u = 0; u < 8; ++u) idx[u] = lcsr[row + j + u];
        float4 av[8];
#pragma unroll
        for (int u = 0; u < 8; ++u) av[u] = p1[idx[u] * 8 + c4];
#pragma unroll
        for (int u = 0; u < 8; ++u) {
          const __half2* h = (const __half2*)&av[u];
#pragma unroll
          for (int m = 0; m < 4; ++m) {
            float2 f = __half22float2(h[m]);
            acc[2 * m] += f.x;
            acc[2 * m + 1] += f.y;
          }
        }
      }
      for (; j < deg; ++j) {
        float4 a = p1[lcsr[row + j] * 8 + c4];
        const __half2* h = (const __half2*)&a;
#pragma unroll
        for (int m = 0; m < 4; ++m) {
          float2 f = __half22float2(h[m]);
          acc[2 * m] += f.x;
          acc[2 * m + 1] += f.y;
        }
      }
      float inv = 1.0f / fmaxf((float)deg, 1.0f);
      float4 qv = q1[n * 8 + c4];
      __half2* qh = (__half2*)&qv;
      union { __half2 h2[2]; float2 f2; } u01, u23;
#pragma unroll
      for (int m = 0; m < 2; ++m) {
        float2 f = __half22float2(qh[m]);
        float2 s;
        s.x = fmaxf(acc[2 * m] * inv + f.x, 0.0f);
        s.y = fmaxf(acc[2 * m + 1] * inv + f.y, 0.0f);
        u01.h2[m] = __float22half2_rn(s);
      }
#pragma unroll
      for (int m = 2; m < 4; ++m) {
        float2 f = __half22float2(qh[m]);
        float2 s;
        s.x = fmaxf(acc[2 * m] * inv + f.x, 0.0f);
        s.y = fmaxf(acc[2 * m + 1] * inv + f.y, 0.0f);
        u23.h2[m - 2] = __float22half2_rn(s);
      }
      *(float2*)&sH[r * 68 + c4 * 8] = u01.f2;
      *(float2*)&sH[r * 68 + c4 * 8 + 4] = u23.f2;
    } else {
      // zero pad rows beyond N_NODES so phase C MFMA reads defined data
      *(float2*)&sH[r * 68 + c4 * 8] = make_float2(0.0f, 0.0f);
      *(float2*)&sH[r * 68 + c4 * 8 + 4] = make_float2(0.0f, 0.0f);
    }
  }
  __syncthreads();

  // ---- Phase C: 16 waves, one 16-row tile each; p2 and q2 per wave ----
  int wv = t >> 6, lane = t & 63;
  int n16 = lane & 15, quad = lane >> 4;
  f32x4 aP, aQ;
#pragma unroll
  for (int r = 0; r < 4; ++r) { aP[r] = 0.0f; aQ[r] = 0.0f; }
  const _Float16* pA = &sH[(wv * 16 + n16) * 68 + quad * 8];
  const _Float16* pBP = &sW[n16 * 68 + quad * 8];
  const _Float16* pBQ = &sW[(16 + n16) * 68 + quad * 8];
#pragma unroll
  for (int kc = 0; kc < 2; ++kc) {
    union { f16x8 v; float2 f2[2]; } a, bp, bq;
    a.f2[0] = *(const float2*)(pA + kc * 32);
    a.f2[1] = *(const float2*)(pA + kc * 32 + 4);
    bp.f2[0] = *(const float2*)(pBP + kc * 32);
    bp.f2[1] = *(const float2*)(pBP + kc * 32 + 4);
    bq.f2[0] = *(const float2*)(pBQ + kc * 32);
    bq.f2[1] = *(const float2*)(pBQ + kc * 32 + 4);
    aP = __builtin_amdgcn_mfma_f32_16x16x32_f16(a.v, bp.v, aP, 0, 0, 0);
    aQ = __builtin_amdgcn_mfma_f32_16x16x32_f16(a.v, bq.v, aQ, 0, 0, 0);
  }
  float bias = b2[n16];
#pragma unroll
  for (int r = 0; r < 4; ++r) {
    int row = wv * 16 + quad * 4 + r;
    int n = (b << BSH) + row;
    if (n < N_NODES) {
      p2[(size_t)n * 16 + n16] = __float2half(aP[r]);
      q2[(size_t)n * 16 + n16] = aQ[r] + bias;
    }
  }
}

// ---------------------------------------------------------------------------
// Fuse 2: out[n] = mean_j p2[csr_j] + q2[n].
// float4 gathers, 2 lanes/node, 8-deep unroll.
// ---------------------------------------------------------------------------
__global__ __launch_bounds__(256) void k_fuse2(
    const float4* __restrict__ p2, const float4* __restrict__ q2,
    const int* __restrict__ rowstart, const int* __restrict__ cnt,
    const int* __restrict__ csr, float4* __restrict__ out) {
  int t = threadIdx.x;
  int n = blockIdx.x * 128 + (t >> 1);
  if (n >= N_NODES) return;
  int c8 = t & 1;
  int row = rowstart[n];
  int deg = cnt[n];
  float acc[8];
#pragma unroll
  for (int m = 0; m < 8; ++m) acc[m] = 0.0f;
  int j = 0;
  for (; j + 8 <= deg; j += 8) {
    int idx[8];
#pragma unroll
    for (int u = 0; u < 8; ++u) idx[u] = csr[row + j + u];
    float4 av[8];
#pragma unroll
    for (int u = 0; u < 8; ++u) av[u] = p2[idx[u] * 2 + c8];
#pragma unroll
    for (int u = 0; u < 8; ++u) {
      const __half2* h = (const __half2*)&av[u];
#pragma unroll
      for (int m = 0; m < 4; ++m) {
        float2 f = __half22float2(h[m]);
        acc[2 * m] += f.x;
        acc[2 * m + 1] += f.y;
      }
    }
  }
  for (; j < deg; ++j) {
    float4 a = p2[csr[row + j] * 2 + c8];
    const __half2* h = (const __half2*)&a;
#pragma unroll
    for (int m = 0; m < 4; ++m) {
      float2 f = __half22float2(h[m]);
      acc[2 * m] += f.x;
      acc[2 * m + 1] += f.y;
    }
  }
  float inv = 1.0f / fmaxf((float)deg, 1.0f);
  float4 q0 = q2[n * 4 + c8 * 2];
  float4 q1v = q2[n * 4 + c8 * 2 + 1];
  float4 o0 = {acc[0] * inv + q0.x, acc[1] * inv + q0.y,
               acc[2] * inv + q0.z, acc[3] * inv + q0.w};
  float4 o1 = {acc[4] * inv + q1v.x, acc[5] * inv + q1v.y,
               acc[6] * inv + q1v.z, acc[7] * inv + q1v.w};
  out[n * 4 + c8 * 2] = o0;
  out[n * 4 + c8 * 2 + 1] = o1;
}

extern "C" void kernel_launch(void* const* d_in, const int* in_sizes, int n_in,
                              void* d_out, int out_size, void* d_ws, size_t ws_size,
                              hipStream_t stream) {
  const float* x   = (const float*)d_in[0];
  const int* edge  = (const int*)d_in[1];
  const int* src   = edge;            // edge_index[0]
  const int* dst   = edge + N_EDGES;  // edge_index[1]
  const float* W1l = (const float*)d_in[2];
  const float* b1  = (const float*)d_in[3];
  const float* W1r = (const float*)d_in[4];
  const float* W2l = (const float*)d_in[5];
  const float* b2  = (const float*)d_in[6];
  const float* W2r = (const float*)d_in[7];
  float* out = (float*)d_out;

  // workspace layout (4-byte units; fp16 bases 16B aligned)
  int* gcnt     = (int*)d_ws;          // NBKT*GSTR = 12512 (pad to 12544)
  int* rowstart = gcnt + 12544;        // 100000
  int* cnt      = rowstart + N_NODES;  // 100000
  int* binned   = cnt + N_NODES;       // NBKT*CAP = 2001920
  int* csr      = binned + NBKT * CAP; // 2001920
  __half* p1    = (__half*)(csr + NBKT * CAP);  // 6.4M halves (12.8 MB)
  __half* q1    = p1 + (size_t)N_NODES * 64;    // 6.4M halves (12.8 MB)
  __half* p2    = q1 + (size_t)N_NODES * 64;    // 1.6M halves (3.2 MB)
  float* q2     = (float*)(p2 + (size_t)N_NODES * 16);  // 1.6M floats (6.4 MB)

  hipMemsetAsync(gcnt, 0, NBKT * GSTR * sizeof(int), stream);

  // 1: bin ∪ gemm1 (independent, one dispatch; bin blocks first)
  k_merged1<<<GB + G1B, 256, 0, stream>>>(src, dst, gcnt, binned,
                                          x, W1l, W1r, b1, p1, q1);
  // 2: finalize ∪ fuse1 ∪ gemm2 (256-node bucket per block, 1024 thr)
  k_fuse1c<<<NBKT, 1024, 0, stream>>>((const float4*)p1, gcnt, binned,
                                      W2l, W2r, b2, (const float4*)q1,
                                      csr, rowstart, cnt, p2, q2);
  // 3: fuse2
  k_fuse2<<<(N_NODES + 127) / 128, 256, 0, stream>>>((const float4*)p2,
                                                     (const float4*)q2,
                                                     rowstart, cnt, csr,
                                                     (float4*)out);
}

// Round 7
// 173.903 us; speedup vs baseline: 1.2397x; 1.0589x over previous
//
#include <hip/hip_runtime.h>
#include <hip/hip_fp16.h>

#define N_NODES 100000
#define N_EDGES 1600000
#define IN_C 64
#define HID_C 64
#define OUT_C 16

#define BKT 256        // nodes per dst bucket
#define BSH 8          // dst >> 8 = bucket
#define NBKT 391       // ceil(100000/256)
#define CAP 5120       // slots per bucket (mean 4092, +16 sigma margin)
#define GSTR 32        // gcnt stride in ints: one counter per 128B line
#define GB 512         // bin sub-blocks in merged pass 1
#define EPB 3125       // edges per bin block (512*3125 = 1.6M exact)
#define NIT 13         // ceil(EPB/256) register-cached edges per thread
#define G1B 1563       // gemm1 sub-blocks = ceil(100000/64)

typedef _Float16 f16x8 __attribute__((ext_vector_type(8)));
typedef float f32x4 __attribute__((ext_vector_type(4)));
typedef float f32x16 __attribute__((ext_vector_type(16)));

// ---------------------------------------------------------------------------
// Merged pass 1 (round-6, best measured): blocks [0,GB) bin edges; blocks
// [GB, GB+G1B) do GEMM1 (MFMA). Bin: dst/src register-cached one-pass,
// 4-way split LDS histogram -> one global atomicAdd per (block,bucket)
// reserves range -> scatter via single cur (contiguous runs).
// ---------------------------------------------------------------------------
__global__ __launch_bounds__(256) void k_merged1(
    const int* __restrict__ src, const int* __restrict__ dst,
    int* __restrict__ gcnt, int* __restrict__ binned,
    const float* __restrict__ x, const float* __restrict__ Wl,
    const float* __restrict__ Wr, const float* __restrict__ b,
    __half* __restrict__ p, __half* __restrict__ q) {
  __shared__ _Float16 sA[64 * 68];    // gemm: [row][k]   | bin: h4[] alias
  __shared__ _Float16 sW[128 * 68];   // gemm: [col][k]^T | bin: cur[] alias
  int t = threadIdx.x;

  if (blockIdx.x < GB) {
    int* h4  = (int*)sA;              // 4*NBKT = 1564 ints (6256B <= 8704B)
    int* cur = (int*)sW;              // NBKT ints
    for (int i = t; i < 4 * NBKT; i += 256) h4[i] = 0;
    __syncthreads();
    int base = blockIdx.x * EPB;
    int end = base + EPB;
    int dv[NIT], sv[NIT];
#pragma unroll
    for (int it = 0; it < NIT; ++it) {
      int e = base + t + it * 256;
      bool ok = (e < end);
      dv[it] = ok ? dst[e] : -1;
      sv[it] = ok ? src[e] : 0;
    }
    int hoff = (t & 3) * NBKT;        // 4-way copy split by lane%4
#pragma unroll
    for (int it = 0; it < NIT; ++it)
      if (dv[it] >= 0) atomicAdd(&h4[hoff + (dv[it] >> BSH)], 1);
    __syncthreads();
    for (int i = t; i < NBKT; i += 256) {
      int c = h4[i] + h4[NBKT + i] + h4[2 * NBKT + i] + h4[3 * NBKT + i];
      int b0 = (c > 0) ? atomicAdd(&gcnt[i * GSTR], c) : 0;  // reserve range
      cur[i] = i * CAP + b0;
    }
    __syncthreads();
#pragma unroll
    for (int it = 0; it < NIT; ++it) {
      if (dv[it] >= 0) {
        int d = dv[it];
        int pos = atomicAdd(&cur[d >> BSH], 1);
        binned[pos] = (sv[it] << BSH) | (d & (BKT - 1));
      }
    }
    return;
  }

  // ---------------- gemm1 body ----------------
  int n0 = (blockIdx.x - GB) * 64;

  for (int f = t; f < 1024; f += 256) {
    int r = f >> 4, c4 = f & 15;
    int n = n0 + r;
    float4 v = {0.0f, 0.0f, 0.0f, 0.0f};
    if (n < N_NODES) v = *(const float4*)&x[(size_t)n * 64 + c4 * 4];
    union { _Float16 h[4]; float2 f2; } u;
    u.h[0] = (_Float16)v.x; u.h[1] = (_Float16)v.y;
    u.h[2] = (_Float16)v.z; u.h[3] = (_Float16)v.w;
    *(float2*)&sA[r * 68 + c4 * 4] = u.f2;
  }
  for (int f = t; f < 2048; f += 256) {
    int k = f >> 5, c4 = f & 31;
    float4 w = (c4 < 16) ? *(const float4*)&Wl[k * 64 + c4 * 4]
                         : *(const float4*)&Wr[k * 64 + (c4 - 16) * 4];
    int c = c4 * 4;
    sW[(c + 0) * 68 + k] = (_Float16)w.x;
    sW[(c + 1) * 68 + k] = (_Float16)w.y;
    sW[(c + 2) * 68 + k] = (_Float16)w.z;
    sW[(c + 3) * 68 + k] = (_Float16)w.w;
  }
  __syncthreads();

  int w = t >> 6, lane = t & 63;
  int m = lane & 31, half = lane >> 5;
  int rt = w & 1, cg = w >> 1;

  f32x16 acc[2];
#pragma unroll
  for (int r = 0; r < 16; ++r) { acc[0][r] = 0.0f; acc[1][r] = 0.0f; }

  const _Float16* pA = &sA[(rt * 32 + m) * 68 + half * 8];
  const _Float16* pB0 = &sW[(cg * 64 + m) * 68 + half * 8];
  const _Float16* pB1 = &sW[(cg * 64 + 32 + m) * 68 + half * 8];
#pragma unroll
  for (int kc = 0; kc < 4; ++kc) {
    union { f16x8 v; float2 f2[2]; } a, b0, b1;
    a.f2[0] = *(const float2*)(pA + kc * 16);
    a.f2[1] = *(const float2*)(pA + kc * 16 + 4);
    b0.f2[0] = *(const float2*)(pB0 + kc * 16);
    b0.f2[1] = *(const float2*)(pB0 + kc * 16 + 4);
    b1.f2[0] = *(const float2*)(pB1 + kc * 16);
    b1.f2[1] = *(const float2*)(pB1 + kc * 16 + 4);
    acc[0] = __builtin_amdgcn_mfma_f32_32x32x16_f16(a.v, b0.v, acc[0], 0, 0, 0);
    acc[1] = __builtin_amdgcn_mfma_f32_32x32x16_f16(a.v, b1.v, acc[1], 0, 0, 0);
  }

  if (cg == 0) {
#pragma unroll
    for (int tt = 0; tt < 2; ++tt) {
      int col = tt * 32 + m;
#pragma unroll
      for (int r = 0; r < 16; ++r) {
        int row = (r & 3) + 4 * half + 8 * (r >> 2);
        int n = n0 + rt * 32 + row;
        if (n < N_NODES) p[(size_t)n * 64 + col] = __float2half(acc[tt][r]);
      }
    }
  } else {
    float bias[2] = {b[m], b[32 + m]};
#pragma unroll
    for (int tt = 0; tt < 2; ++tt) {
      int col = tt * 32 + m;
#pragma unroll
      for (int r = 0; r < 16; ++r) {
        int row = (r & 3) + 4 * half + 8 * (r >> 2);
        int n = n0 + rt * 32 + row;
        if (n < N_NODES)
          q[(size_t)n * 64 + col] = __float2half(acc[tt][r] + bias[tt]);
      }
    }
  }
}

// ---------------------------------------------------------------------------
// Fuse1c (finalize ∪ fuse1 ∪ gemm2): one block per 256-node bucket, 1024 thr.
// Phase A: reg-cached binned (ev[5]) -> LDS histogram -> wave shfl scan ->
//          scatter into LDS lcsr; export csr/rowstart/cnt for fuse2.
// Phase B: h = relu(mean_j p1[lcsr_j] + q1) -> fp16 LDS sH. Gather is
//          DUAL-BUFFERED batch-4 (issue batch k+1 before consuming batch k)
//          to break the per-batch full-latency stall. Batch-4 (not 8) keeps
//          VGPR <= 64 so 2 blocks/CU (16 waves/block) is preserved.
// Phase C: MFMA 256x32 K=64: 16 waves x one 16-row tile.
// ---------------------------------------------------------------------------
__global__ __launch_bounds__(1024) void k_fuse1c(
    const float4* __restrict__ p1, const int* __restrict__ gcnt,
    const int* __restrict__ binned, const float* __restrict__ W2l,
    const float* __restrict__ W2r, const float* __restrict__ b2,
    const float4* __restrict__ q1, int* __restrict__ csr,
    int* __restrict__ rowstart, int* __restrict__ cnt,
    __half* __restrict__ p2, float* __restrict__ q2) {
  __shared__ int hcnt[BKT];
  __shared__ int hscan[BKT];
  __shared__ int cur[BKT];
  __shared__ int lcsr[CAP];          // 20 KB
  __shared__ _Float16 sH[256 * 68];  // 34.8 KB
  __shared__ _Float16 sW[32 * 68];   // 4.4 KB [col][k]^T: 0-15 W2l, 16-31 W2r
  int b = blockIdx.x;
  int t = threadIdx.x;

  if (t < 512) {  // stage W2^T (512 half4 chunks)
    int k = t >> 3, c4v = t & 7;
    float4 w = (c4v < 4) ? *(const float4*)&W2l[k * 16 + c4v * 4]
                         : *(const float4*)&W2r[k * 16 + (c4v - 4) * 4];
    int c = c4v * 4;
    sW[(c + 0) * 68 + k] = (_Float16)w.x;
    sW[(c + 1) * 68 + k] = (_Float16)w.y;
    sW[(c + 2) * 68 + k] = (_Float16)w.z;
    sW[(c + 3) * 68 + k] = (_Float16)w.w;
  }
  if (t < BKT) hcnt[t] = 0;
  __syncthreads();

  // ---- Phase A ----
  int start = b * CAP;
  int total = gcnt[b * GSTR];
  int ev[5];
#pragma unroll
  for (int u = 0; u < 5; ++u) {       // one global read pass, reg-cached
    int i = t + u * 1024;
    ev[u] = (i < total) ? binned[start + i] : -1;
  }
#pragma unroll
  for (int u = 0; u < 5; ++u)
    if (ev[u] >= 0) atomicAdd(&hcnt[ev[u] & (BKT - 1)], 1);
  __syncthreads();
  if (t < 64) {  // single-wave inclusive scan of 256 counters (4 segments)
    int s0 = hcnt[t], s1 = hcnt[64 + t], s2 = hcnt[128 + t], s3 = hcnt[192 + t];
    for (int st = 1; st < 64; st <<= 1) {
      int a0 = __shfl_up(s0, st), a1 = __shfl_up(s1, st);
      int a2 = __shfl_up(s2, st), a3 = __shfl_up(s3, st);
      if (t >= st) { s0 += a0; s1 += a1; s2 += a2; s3 += a3; }
    }
    int t0 = __shfl(s0, 63), t1 = __shfl(s1, 63), t2 = __shfl(s2, 63);
    hscan[t] = s0;
    hscan[64 + t] = s1 + t0;
    hscan[128 + t] = s2 + t0 + t1;
    hscan[192 + t] = s3 + t0 + t1 + t2;
  }
  __syncthreads();
  if (t < BKT) {
    int v = hcnt[t];
    int e0 = hscan[t] - v;          // local exclusive start
    cur[t] = e0;
    int n = (b << BSH) + t;
    if (n < N_NODES) {
      rowstart[n] = start + e0;
      cnt[n] = v;
    }
  }
  __syncthreads();
#pragma unroll
  for (int u = 0; u < 5; ++u) {
    if (ev[u] >= 0) {
      int vv = ev[u];
      int pos = atomicAdd(&cur[vv & (BKT - 1)], 1);
      lcsr[pos] = vv >> BSH;
    }
  }
  __syncthreads();
  for (int i = t; i < total; i += 1024) csr[start + i] = lcsr[i];  // for fuse2

  // ---- Phase B: aggregate + relu -> sH (fp16); 128 groups x 2 nodes ----
  int g = t >> 3, c4 = t & 7;
  for (int r = g; r < BKT; r += 128) {
    int n = (b << BSH) + r;
    if (n < N_NODES) {
      int deg = hcnt[r];
      int row = hscan[r] - deg;  // local start in lcsr
      float acc[8];
#pragma unroll
      for (int m = 0; m < 8; ++m) acc[m] = 0.0f;
      int j = 0;
      if (deg >= 4) {  // dual-buffered batch-4 gather pipeline
        float4 avA[4];
        {
          int idx[4];
#pragma unroll
          for (int u = 0; u < 4; ++u) idx[u] = lcsr[row + u];
#pragma unroll
          for (int u = 0; u < 4; ++u) avA[u] = p1[idx[u] * 8 + c4];
        }
        for (j = 4; j + 4 <= deg; j += 4) {
          int idx[4];
          float4 avB[4];
#pragma unroll
          for (int u = 0; u < 4; ++u) idx[u] = lcsr[row + j + u];
#pragma unroll
          for (int u = 0; u < 4; ++u) avB[u] = p1[idx[u] * 8 + c4];
          // consume previous batch while this one is in flight
#pragma unroll
          for (int u = 0; u < 4; ++u) {
            const __half2* h = (const __half2*)&avA[u];
#pragma unroll
            for (int m = 0; m < 4; ++m) {
              float2 f = __half22float2(h[m]);
              acc[2 * m] += f.x;
              acc[2 * m + 1] += f.y;
            }
          }
#pragma unroll
          for (int u = 0; u < 4; ++u) avA[u] = avB[u];
        }
#pragma unroll
        for (int u = 0; u < 4; ++u) {
          const __half2* h = (const __half2*)&avA[u];
#pragma unroll
          for (int m = 0; m < 4; ++m) {
            float2 f = __half22float2(h[m]);
            acc[2 * m] += f.x;
            acc[2 * m + 1] += f.y;
          }
        }
      }
      for (; j < deg; ++j) {
        float4 a = p1[lcsr[row + j] * 8 + c4];
        const __half2* h = (const __half2*)&a;
#pragma unroll
        for (int m = 0; m < 4; ++m) {
          float2 f = __half22float2(h[m]);
          acc[2 * m] += f.x;
          acc[2 * m + 1] += f.y;
        }
      }
      float inv = 1.0f / fmaxf((float)deg, 1.0f);
      float4 qv = q1[n * 8 + c4];
      __half2* qh = (__half2*)&qv;
      union { __half2 h2[2]; float2 f2; } u01, u23;
#pragma unroll
      for (int m = 0; m < 2; ++m) {
        float2 f = __half22float2(qh[m]);
        float2 s;
        s.x = fmaxf(acc[2 * m] * inv + f.x, 0.0f);
        s.y = fmaxf(acc[2 * m + 1] * inv + f.y, 0.0f);
        u01.h2[m] = __float22half2_rn(s);
      }
#pragma unroll
      for (int m = 2; m < 4; ++m) {
        float2 f = __half22float2(qh[m]);
        float2 s;
        s.x = fmaxf(acc[2 * m] * inv + f.x, 0.0f);
        s.y = fmaxf(acc[2 * m + 1] * inv + f.y, 0.0f);
        u23.h2[m - 2] = __float22half2_rn(s);
      }
      *(float2*)&sH[r * 68 + c4 * 8] = u01.f2;
      *(float2*)&sH[r * 68 + c4 * 8 + 4] = u23.f2;
    } else {
      // zero pad rows beyond N_NODES so phase C MFMA reads defined data
      *(float2*)&sH[r * 68 + c4 * 8] = make_float2(0.0f, 0.0f);
      *(float2*)&sH[r * 68 + c4 * 8 + 4] = make_float2(0.0f, 0.0f);
    }
  }
  __syncthreads();

  // ---- Phase C: 16 waves, one 16-row tile each; p2 and q2 per wave ----
  int wv = t >> 6, lane = t & 63;
  int n16 = lane & 15, quad = lane >> 4;
  f32x4 aP, aQ;
#pragma unroll
  for (int r = 0; r < 4; ++r) { aP[r] = 0.0f; aQ[r] = 0.0f; }
  const _Float16* pA = &sH[(wv * 16 + n16) * 68 + quad * 8];
  const _Float16* pBP = &sW[n16 * 68 + quad * 8];
  const _Float16* pBQ = &sW[(16 + n16) * 68 + quad * 8];
#pragma unroll
  for (int kc = 0; kc < 2; ++kc) {
    union { f16x8 v; float2 f2[2]; } a, bp, bq;
    a.f2[0] = *(const float2*)(pA + kc * 32);
    a.f2[1] = *(const float2*)(pA + kc * 32 + 4);
    bp.f2[0] = *(const float2*)(pBP + kc * 32);
    bp.f2[1] = *(const float2*)(pBP + kc * 32 + 4);
    bq.f2[0] = *(const float2*)(pBQ + kc * 32);
    bq.f2[1] = *(const float2*)(pBQ + kc * 32 + 4);
    aP = __builtin_amdgcn_mfma_f32_16x16x32_f16(a.v, bp.v, aP, 0, 0, 0);
    aQ = __builtin_amdgcn_mfma_f32_16x16x32_f16(a.v, bq.v, aQ, 0, 0, 0);
  }
  float bias = b2[n16];
#pragma unroll
  for (int r = 0; r < 4; ++r) {
    int row = wv * 16 + quad * 4 + r;
    int n = (b << BSH) + row;
    if (n < N_NODES) {
      p2[(size_t)n * 16 + n16] = __float2half(aP[r]);
      q2[(size_t)n * 16 + n16] = aQ[r] + bias;
    }
  }
}

// ---------------------------------------------------------------------------
// Fuse 2: out[n] = mean_j p2[csr_j] + q2[n].
// float4 gathers, 2 lanes/node, DUAL-BUFFERED batch-8 pipeline (issue batch
// k+1's loads before consuming batch k). 782 blocks need only ~3/CU, so the
// extra ~32 VGPR cannot cost resident blocks.
// ---------------------------------------------------------------------------
__global__ __launch_bounds__(256) void k_fuse2(
    const float4* __restrict__ p2, const float4* __restrict__ q2,
    const int* __restrict__ rowstart, const int* __restrict__ cnt,
    const int* __restrict__ csr, float4* __restrict__ out) {
  int t = threadIdx.x;
  int n = blockIdx.x * 128 + (t >> 1);
  if (n >= N_NODES) return;
  int c8 = t & 1;
  int row = rowstart[n];
  int deg = cnt[n];
  float acc[8];
#pragma unroll
  for (int m = 0; m < 8; ++m) acc[m] = 0.0f;
  int j = 0;
  if (deg >= 8) {  // dual-buffered batch-8 gather pipeline
    float4 avA[8];
    {
      int idx[8];
#pragma unroll
      for (int u = 0; u < 8; ++u) idx[u] = csr[row + u];
#pragma unroll
      for (int u = 0; u < 8; ++u) avA[u] = p2[idx[u] * 2 + c8];
    }
    for (j = 8; j + 8 <= deg; j += 8) {
      int idx[8];
      float4 avB[8];
#pragma unroll
      for (int u = 0; u < 8; ++u) idx[u] = csr[row + j + u];
#pragma unroll
      for (int u = 0; u < 8; ++u) avB[u] = p2[idx[u] * 2 + c8];
#pragma unroll
      for (int u = 0; u < 8; ++u) {
        const __half2* h = (const __half2*)&avA[u];
#pragma unroll
        for (int m = 0; m < 4; ++m) {
          float2 f = __half22float2(h[m]);
          acc[2 * m] += f.x;
          acc[2 * m + 1] += f.y;
        }
      }
#pragma unroll
      for (int u = 0; u < 8; ++u) avA[u] = avB[u];
    }
#pragma unroll
    for (int u = 0; u < 8; ++u) {
      const __half2* h = (const __half2*)&avA[u];
#pragma unroll
      for (int m = 0; m < 4; ++m) {
        float2 f = __half22float2(h[m]);
        acc[2 * m] += f.x;
        acc[2 * m + 1] += f.y;
      }
    }
  }
  for (; j < deg; ++j) {
    float4 a = p2[csr[row + j] * 2 + c8];
    const __half2* h = (const __half2*)&a;
#pragma unroll
    for (int m = 0; m < 4; ++m) {
      float2 f = __half22float2(h[m]);
      acc[2 * m] += f.x;
      acc[2 * m + 1] += f.y;
    }
  }
  float inv = 1.0f / fmaxf((float)deg, 1.0f);
  float4 q0 = q2[n * 4 + c8 * 2];
  float4 q1v = q2[n * 4 + c8 * 2 + 1];
  float4 o0 = {acc[0] * inv + q0.x, acc[1] * inv + q0.y,
               acc[2] * inv + q0.z, acc[3] * inv + q0.w};
  float4 o1 = {acc[4] * inv + q1v.x, acc[5] * inv + q1v.y,
               acc[6] * inv + q1v.z, acc[7] * inv + q1v.w};
  out[n * 4 + c8 * 2] = o0;
  out[n * 4 + c8 * 2 + 1] = o1;
}

extern "C" void kernel_launch(void* const* d_in, const int* in_sizes, int n_in,
                              void* d_out, int out_size, void* d_ws, size_t ws_size,
                              hipStream_t stream) {
  const float* x   = (const float*)d_in[0];
  const int* edge  = (const int*)d_in[1];
  const int* src   = edge;            // edge_index[0]
  const int* dst   = edge + N_EDGES;  // edge_index[1]
  const float* W1l = (const float*)d_in[2];
  const float* b1  = (const float*)d_in[3];
  const float* W1r = (const float*)d_in[4];
  const float* W2l = (const float*)d_in[5];
  const float* b2  = (const float*)d_in[6];
  const float* W2r = (const float*)d_in[7];
  float* out = (float*)d_out;

  // workspace layout (4-byte units; fp16 bases 16B aligned)
  int* gcnt     = (int*)d_ws;          // NBKT*GSTR = 12512 (pad to 12544)
  int* rowstart = gcnt + 12544;        // 100000
  int* cnt      = rowstart + N_NODES;  // 100000
  int* binned   = cnt + N_NODES;       // NBKT*CAP = 2001920
  int* csr      = binned + NBKT * CAP; // 2001920
  __half* p1    = (__half*)(csr + NBKT * CAP);  // 6.4M halves (12.8 MB)
  __half* q1    = p1 + (size_t)N_NODES * 64;    // 6.4M halves (12.8 MB)
  __half* p2    = q1 + (size_t)N_NODES * 64;    // 1.6M halves (3.2 MB)
  float* q2     = (float*)(p2 + (size_t)N_NODES * 16);  // 1.6M floats (6.4 MB)

  hipMemsetAsync(gcnt, 0, NBKT * GSTR * sizeof(int), stream);

  // 1: bin ∪ gemm1 (independent, one dispatch; bin blocks first)
  k_merged1<<<GB + G1B, 256, 0, stream>>>(src, dst, gcnt, binned,
                                          x, W1l, W1r, b1, p1, q1);
  // 2: finalize ∪ fuse1 ∪ gemm2 (256-node bucket per block, 1024 thr)
  k_fuse1c<<<NBKT, 1024, 0, stream>>>((const float4*)p1, gcnt, binned,
                                      W2l, W2r, b2, (const float4*)q1,
                                      csr, rowstart, cnt, p2, q2);
  // 3: fuse2
  k_fuse2<<<(N_NODES + 127) / 128, 256, 0, stream>>>((const float4*)p2,
                                                     (const float4*)q2,
                                                     rowstart, cnt, csr,
                                                     (float4*)out);
}

// Round 9
// 173.888 us; speedup vs baseline: 1.2398x; 1.0001x over previous
//
#include <hip/hip_runtime.h>
#include <hip/hip_fp16.h>

#define N_NODES 100000
#define N_EDGES 1600000
#define IN_C 64
#define HID_C 64
#define OUT_C 16

#define BKT 256        // nodes per dst bucket
#define BSH 8          // dst >> 8 = bucket
#define NBKT 391       // ceil(100000/256)
#define CAP 5120       // slots per bucket (mean 4092, +16 sigma margin)
#define GSTR 32        // gcnt stride in ints: one counter per 128B line
#define GB 512         // bin sub-blocks in merged pass 1
#define EPB 3125       // edges per bin block (512*3125 = 1.6M exact)
#define NIT 13         // ceil(EPB/256) register-cached edges per thread
#define G1B 1563       // gemm1 sub-blocks = ceil(100000/64)

typedef _Float16 f16x8 __attribute__((ext_vector_type(8)));
typedef float f32x4 __attribute__((ext_vector_type(4)));
typedef float f32x16 __attribute__((ext_vector_type(16)));

// ---------------------------------------------------------------------------
// Merged pass 1 (round-6/7, best measured): blocks [0,GB) bin edges; blocks
// [GB, GB+G1B) do GEMM1 (MFMA). Bin: dst/src register-cached one-pass,
// 4-way split LDS histogram -> one global atomicAdd per (block,bucket)
// reserves range -> scatter via single cur (contiguous runs).
// ---------------------------------------------------------------------------
__global__ __launch_bounds__(256) void k_merged1(
    const int* __restrict__ src, const int* __restrict__ dst,
    int* __restrict__ gcnt, int* __restrict__ binned,
    const float* __restrict__ x, const float* __restrict__ Wl,
    const float* __restrict__ Wr, const float* __restrict__ b,
    __half* __restrict__ p, __half* __restrict__ q) {
  __shared__ _Float16 sA[64 * 68];    // gemm: [row][k]   | bin: h4[] alias
  __shared__ _Float16 sW[128 * 68];   // gemm: [col][k]^T | bin: cur[] alias
  int t = threadIdx.x;

  if (blockIdx.x < GB) {
    int* h4  = (int*)sA;              // 4*NBKT = 1564 ints (6256B <= 8704B)
    int* cur = (int*)sW;              // NBKT ints
    for (int i = t; i < 4 * NBKT; i += 256) h4[i] = 0;
    __syncthreads();
    int base = blockIdx.x * EPB;
    int end = base + EPB;
    int dv[NIT], sv[NIT];
#pragma unroll
    for (int it = 0; it < NIT; ++it) {
      int e = base + t + it * 256;
      bool ok = (e < end);
      dv[it] = ok ? dst[e] : -1;
      sv[it] = ok ? src[e] : 0;
    }
    int hoff = (t & 3) * NBKT;        // 4-way copy split by lane%4
#pragma unroll
    for (int it = 0; it < NIT; ++it)
      if (dv[it] >= 0) atomicAdd(&h4[hoff + (dv[it] >> BSH)], 1);
    __syncthreads();
    for (int i = t; i < NBKT; i += 256) {
      int c = h4[i] + h4[NBKT + i] + h4[2 * NBKT + i] + h4[3 * NBKT + i];
      int b0 = (c > 0) ? atomicAdd(&gcnt[i * GSTR], c) : 0;  // reserve range
      cur[i] = i * CAP + b0;
    }
    __syncthreads();
#pragma unroll
    for (int it = 0; it < NIT; ++it) {
      if (dv[it] >= 0) {
        int d = dv[it];
        int pos = atomicAdd(&cur[d >> BSH], 1);
        binned[pos] = (sv[it] << BSH) | (d & (BKT - 1));
      }
    }
    return;
  }

  // ---------------- gemm1 body ----------------
  int n0 = (blockIdx.x - GB) * 64;

  for (int f = t; f < 1024; f += 256) {
    int r = f >> 4, c4 = f & 15;
    int n = n0 + r;
    float4 v = {0.0f, 0.0f, 0.0f, 0.0f};
    if (n < N_NODES) v = *(const float4*)&x[(size_t)n * 64 + c4 * 4];
    union { _Float16 h[4]; float2 f2; } u;
    u.h[0] = (_Float16)v.x; u.h[1] = (_Float16)v.y;
    u.h[2] = (_Float16)v.z; u.h[3] = (_Float16)v.w;
    *(float2*)&sA[r * 68 + c4 * 4] = u.f2;
  }
  for (int f = t; f < 2048; f += 256) {
    int k = f >> 5, c4 = f & 31;
    float4 w = (c4 < 16) ? *(const float4*)&Wl[k * 64 + c4 * 4]
                         : *(const float4*)&Wr[k * 64 + (c4 - 16) * 4];
    int c = c4 * 4;
    sW[(c + 0) * 68 + k] = (_Float16)w.x;
    sW[(c + 1) * 68 + k] = (_Float16)w.y;
    sW[(c + 2) * 68 + k] = (_Float16)w.z;
    sW[(c + 3) * 68 + k] = (_Float16)w.w;
  }
  __syncthreads();

  int w = t >> 6, lane = t & 63;
  int m = lane & 31, half = lane >> 5;
  int rt = w & 1, cg = w >> 1;

  f32x16 acc[2];
#pragma unroll
  for (int r = 0; r < 16; ++r) { acc[0][r] = 0.0f; acc[1][r] = 0.0f; }

  const _Float16* pA = &sA[(rt * 32 + m) * 68 + half * 8];
  const _Float16* pB0 = &sW[(cg * 64 + m) * 68 + half * 8];
  const _Float16* pB1 = &sW[(cg * 64 + 32 + m) * 68 + half * 8];
#pragma unroll
  for (int kc = 0; kc < 4; ++kc) {
    union { f16x8 v; float2 f2[2]; } a, b0, b1;
    a.f2[0] = *(const float2*)(pA + kc * 16);
    a.f2[1] = *(const float2*)(pA + kc * 16 + 4);
    b0.f2[0] = *(const float2*)(pB0 + kc * 16);
    b0.f2[1] = *(const float2*)(pB0 + kc * 16 + 4);
    b1.f2[0] = *(const float2*)(pB1 + kc * 16);
    b1.f2[1] = *(const float2*)(pB1 + kc * 16 + 4);
    acc[0] = __builtin_amdgcn_mfma_f32_32x32x16_f16(a.v, b0.v, acc[0], 0, 0, 0);
    acc[1] = __builtin_amdgcn_mfma_f32_32x32x16_f16(a.v, b1.v, acc[1], 0, 0, 0);
  }

  if (cg == 0) {
#pragma unroll
    for (int tt = 0; tt < 2; ++tt) {
      int col = tt * 32 + m;
#pragma unroll
      for (int r = 0; r < 16; ++r) {
        int row = (r & 3) + 4 * half + 8 * (r >> 2);
        int n = n0 + rt * 32 + row;
        if (n < N_NODES) p[(size_t)n * 64 + col] = __float2half(acc[tt][r]);
      }
    }
  } else {
    float bias[2] = {b[m], b[32 + m]};
#pragma unroll
    for (int tt = 0; tt < 2; ++tt) {
      int col = tt * 32 + m;
#pragma unroll
      for (int r = 0; r < 16; ++r) {
        int row = (r & 3) + 4 * half + 8 * (r >> 2);
        int n = n0 + rt * 32 + row;
        if (n < N_NODES)
          q[(size_t)n * 64 + col] = __float2half(acc[tt][r] + bias[tt]);
      }
    }
  }
}

// ---------------------------------------------------------------------------
// Fuse1c (finalize ∪ fuse1 ∪ gemm2): one block per 256-node bucket, 1024 thr.
// Phase A: reg-cached binned (ev[5]) -> LDS histogram -> wave shfl scan ->
//          scatter into LDS lcsr; export csr/rowstart/cnt for fuse2.
// Phase B: h = relu(mean_j p1[lcsr_j] + q1) -> fp16 LDS sH.
//          16 threads/node: 8 channel-lanes x 2 deg-halves; each half runs a
//          DUAL-BUFFERED batch-4 gather pipeline; halves combined in-wave via
//          __shfl_xor(acc, 8). Serial gather chain per thread: deg -> deg/2.
// Phase C: MFMA 256x32 K=64: 16 waves x one 16-row tile.
// ---------------------------------------------------------------------------
__global__ __launch_bounds__(1024) void k_fuse1c(
    const float4* __restrict__ p1, const int* __restrict__ gcnt,
    const int* __restrict__ binned, const float* __restrict__ W2l,
    const float* __restrict__ W2r, const float* __restrict__ b2,
    const float4* __restrict__ q1, int* __restrict__ csr,
    int* __restrict__ rowstart, int* __restrict__ cnt,
    __half* __restrict__ p2, float* __restrict__ q2) {
  __shared__ int hcnt[BKT];
  __shared__ int hscan[BKT];
  __shared__ int cur[BKT];
  __shared__ int lcsr[CAP];          // 20 KB
  __shared__ _Float16 sH[256 * 68];  // 34.8 KB
  __shared__ _Float16 sW[32 * 68];   // 4.4 KB [col][k]^T: 0-15 W2l, 16-31 W2r
  int b = blockIdx.x;
  int t = threadIdx.x;

  if (t < 512) {  // stage W2^T (512 half4 chunks)
    int k = t >> 3, c4v = t & 7;
    float4 w = (c4v < 4) ? *(const float4*)&W2l[k * 16 + c4v * 4]
                         : *(const float4*)&W2r[k * 16 + (c4v - 4) * 4];
    int c = c4v * 4;
    sW[(c + 0) * 68 + k] = (_Float16)w.x;
    sW[(c + 1) * 68 + k] = (_Float16)w.y;
    sW[(c + 2) * 68 + k] = (_Float16)w.z;
    sW[(c + 3) * 68 + k] = (_Float16)w.w;
  }
  if (t < BKT) hcnt[t] = 0;
  __syncthreads();

  // ---- Phase A ----
  int start = b * CAP;
  int total = gcnt[b * GSTR];
  int ev[5];
#pragma unroll
  for (int u = 0; u < 5; ++u) {       // one global read pass, reg-cached
    int i = t + u * 1024;
    ev[u] = (i < total) ? binned[start + i] : -1;
  }
#pragma unroll
  for (int u = 0; u < 5; ++u)
    if (ev[u] >= 0) atomicAdd(&hcnt[ev[u] & (BKT - 1)], 1);
  __syncthreads();
  if (t < 64) {  // single-wave inclusive scan of 256 counters (4 segments)
    int s0 = hcnt[t], s1 = hcnt[64 + t], s2 = hcnt[128 + t], s3 = hcnt[192 + t];
    for (int st = 1; st < 64; st <<= 1) {
      int a0 = __shfl_up(s0, st), a1 = __shfl_up(s1, st);
      int a2 = __shfl_up(s2, st), a3 = __shfl_up(s3, st);
      if (t >= st) { s0 += a0; s1 += a1; s2 += a2; s3 += a3; }
    }
    int t0 = __shfl(s0, 63), t1 = __shfl(s1, 63), t2 = __shfl(s2, 63);
    hscan[t] = s0;
    hscan[64 + t] = s1 + t0;
    hscan[128 + t] = s2 + t0 + t1;
    hscan[192 + t] = s3 + t0 + t1 + t2;
  }
  __syncthreads();
  if (t < BKT) {
    int v = hcnt[t];
    int e0 = hscan[t] - v;          // local exclusive start
    cur[t] = e0;
    int n = (b << BSH) + t;
    if (n < N_NODES) {
      rowstart[n] = start + e0;
      cnt[n] = v;
    }
  }
  __syncthreads();
#pragma unroll
  for (int u = 0; u < 5; ++u) {
    if (ev[u] >= 0) {
      int vv = ev[u];
      int pos = atomicAdd(&cur[vv & (BKT - 1)], 1);
      lcsr[pos] = vv >> BSH;
    }
  }
  __syncthreads();
  for (int i = t; i < total; i += 1024) csr[start + i] = lcsr[i];  // for fuse2

  // ---- Phase B: aggregate + relu -> sH; 64 groups x 16 thr/node ----
  int g = t >> 4, c4 = t & 7, dh = (t >> 3) & 1;
  for (int r = g; r < BKT; r += 64) {
    int n = (b << BSH) + r;
    if (n < N_NODES) {
      int deg = hcnt[r];
      int row = hscan[r] - deg;      // local start in lcsr
      int dmid = (deg + 1) >> 1;
      int jb = dh ? dmid : 0;
      int je = dh ? deg : dmid;
      float acc[8];
#pragma unroll
      for (int m = 0; m < 8; ++m) acc[m] = 0.0f;
      int j = jb;
      if (je - jb >= 4) {  // dual-buffered batch-4 gather pipeline
        float4 avA[4];
        {
          int idx[4];
#pragma unroll
          for (int u = 0; u < 4; ++u) idx[u] = lcsr[row + jb + u];
#pragma unroll
          for (int u = 0; u < 4; ++u) avA[u] = p1[idx[u] * 8 + c4];
        }
        for (j = jb + 4; j + 4 <= je; j += 4) {
          int idx[4];
          float4 avB[4];
#pragma unroll
          for (int u = 0; u < 4; ++u) idx[u] = lcsr[row + j + u];
#pragma unroll
          for (int u = 0; u < 4; ++u) avB[u] = p1[idx[u] * 8 + c4];
#pragma unroll
          for (int u = 0; u < 4; ++u) {
            const __half2* h = (const __half2*)&avA[u];
#pragma unroll
            for (int m = 0; m < 4; ++m) {
              float2 f = __half22float2(h[m]);
              acc[2 * m] += f.x;
              acc[2 * m + 1] += f.y;
            }
          }
#pragma unroll
          for (int u = 0; u < 4; ++u) avA[u] = avB[u];
        }
#pragma unroll
        for (int u = 0; u < 4; ++u) {
          const __half2* h = (const __half2*)&avA[u];
#pragma unroll
          for (int m = 0; m < 4; ++m) {
            float2 f = __half22float2(h[m]);
            acc[2 * m] += f.x;
            acc[2 * m + 1] += f.y;
          }
        }
      }
      for (; j < je; ++j) {
        float4 a = p1[lcsr[row + j] * 8 + c4];
        const __half2* h = (const __half2*)&a;
#pragma unroll
        for (int m = 0; m < 4; ++m) {
          float2 f = __half22float2(h[m]);
          acc[2 * m] += f.x;
          acc[2 * m + 1] += f.y;
        }
      }
      // combine the two deg-halves (lanes t and t^8 are in the same wave)
#pragma unroll
      for (int m = 0; m < 8; ++m) acc[m] += __shfl_xor(acc[m], 8);
      if (dh == 0) {
        float inv = 1.0f / fmaxf((float)deg, 1.0f);
        float4 qv = q1[n * 8 + c4];
        __half2* qh = (__half2*)&qv;
        union { __half2 h2[2]; float2 f2; } u01, u23;
#pragma unroll
        for (int m = 0; m < 2; ++m) {
          float2 f = __half22float2(qh[m]);
          float2 s;
          s.x = fmaxf(acc[2 * m] * inv + f.x, 0.0f);
          s.y = fmaxf(acc[2 * m + 1] * inv + f.y, 0.0f);
          u01.h2[m] = __float22half2_rn(s);
        }
#pragma unroll
        for (int m = 2; m < 4; ++m) {
          float2 f = __half22float2(qh[m]);
          float2 s;
          s.x = fmaxf(acc[2 * m] * inv + f.x, 0.0f);
          s.y = fmaxf(acc[2 * m + 1] * inv + f.y, 0.0f);
          u23.h2[m - 2] = __float22half2_rn(s);
        }
        *(float2*)&sH[r * 68 + c4 * 8] = u01.f2;
        *(float2*)&sH[r * 68 + c4 * 8 + 4] = u23.f2;
      }
    } else if (dh == 0) {
      // zero pad rows beyond N_NODES so phase C MFMA reads defined data
      *(float2*)&sH[r * 68 + c4 * 8] = make_float2(0.0f, 0.0f);
      *(float2*)&sH[r * 68 + c4 * 8 + 4] = make_float2(0.0f, 0.0f);
    }
  }
  __syncthreads();

  // ---- Phase C: 16 waves, one 16-row tile each; p2 and q2 per wave ----
  int wv = t >> 6, lane = t & 63;
  int n16 = lane & 15, quad = lane >> 4;
  f32x4 aP, aQ;
#pragma unroll
  for (int r = 0; r < 4; ++r) { aP[r] = 0.0f; aQ[r] = 0.0f; }
  const _Float16* pA = &sH[(wv * 16 + n16) * 68 + quad * 8];
  const _Float16* pBP = &sW[n16 * 68 + quad * 8];
  const _Float16* pBQ = &sW[(16 + n16) * 68 + quad * 8];
#pragma unroll
  for (int kc = 0; kc < 2; ++kc) {
    union { f16x8 v; float2 f2[2]; } a, bp, bq;
    a.f2[0] = *(const float2*)(pA + kc * 32);
    a.f2[1] = *(const float2*)(pA + kc * 32 + 4);
    bp.f2[0] = *(const float2*)(pBP + kc * 32);
    bp.f2[1] = *(const float2*)(pBP + kc * 32 + 4);
    bq.f2[0] = *(const float2*)(pBQ + kc * 32);
    bq.f2[1] = *(const float2*)(pBQ + kc * 32 + 4);
    aP = __builtin_amdgcn_mfma_f32_16x16x32_f16(a.v, bp.v, aP, 0, 0, 0);
    aQ = __builtin_amdgcn_mfma_f32_16x16x32_f16(a.v, bq.v, aQ, 0, 0, 0);
  }
  float bias = b2[n16];
#pragma unroll
  for (int r = 0; r < 4; ++r) {
    int row = wv * 16 + quad * 4 + r;
    int n = (b << BSH) + row;
    if (n < N_NODES) {
      p2[(size_t)n * 16 + n16] = __float2half(aP[r]);
      q2[(size_t)n * 16 + n16] = aQ[r] + bias;
    }
  }
}

// ---------------------------------------------------------------------------
// Fuse 2: out[n] = mean_j p2[csr_j] + q2[n].
// 4 threads/node: 2 channel-lanes (float4 each) x 2 deg-halves; each half
// runs a dual-buffered batch-4 gather pipeline; halves combined in-wave via
// __shfl_xor(acc, 2). 64 nodes per 256-thr block, grid 1563.
// ---------------------------------------------------------------------------
__global__ __launch_bounds__(256) void k_fuse2(
    const float4* __restrict__ p2, const float4* __restrict__ q2,
    const int* __restrict__ rowstart, const int* __restrict__ cnt,
    const int* __restrict__ csr, float4* __restrict__ out) {
  int t = threadIdx.x;
  int n = blockIdx.x * 64 + (t >> 2);
  if (n >= N_NODES) return;
  int c8 = t & 1, dh = (t >> 1) & 1;
  int row = rowstart[n];
  int deg = cnt[n];
  int dmid = (deg + 1) >> 1;
  int jb = dh ? dmid : 0;
  int je = dh ? deg : dmid;
  float acc[8];
#pragma unroll
  for (int m = 0; m < 8; ++m) acc[m] = 0.0f;
  int j = jb;
  if (je - jb >= 4) {  // dual-buffered batch-4 gather pipeline
    float4 avA[4];
    {
      int idx[4];
#pragma unroll
      for (int u = 0; u < 4; ++u) idx[u] = csr[row + jb + u];
#pragma unroll
      for (int u = 0; u < 4; ++u) avA[u] = p2[idx[u] * 2 + c8];
    }
    for (j = jb + 4; j + 4 <= je; j += 4) {
      int idx[4];
      float4 avB[4];
#pragma unroll
      for (int u = 0; u < 4; ++u) idx[u] = csr[row + j + u];
#pragma unroll
      for (int u = 0; u < 4; ++u) avB[u] = p2[idx[u] * 2 + c8];
#pragma unroll
      for (int u = 0; u < 4; ++u) {
        const __half2* h = (const __half2*)&avA[u];
#pragma unroll
        for (int m = 0; m < 4; ++m) {
          float2 f = __half22float2(h[m]);
          acc[2 * m] += f.x;
          acc[2 * m + 1] += f.y;
        }
      }
#pragma unroll
      for (int u = 0; u < 4; ++u) avA[u] = avB[u];
    }
#pragma unroll
    for (int u = 0; u < 4; ++u) {
      const __half2* h = (const __half2*)&avA[u];
#pragma unroll
      for (int m = 0; m < 4; ++m) {
        float2 f = __half22float2(h[m]);
        acc[2 * m] += f.x;
        acc[2 * m + 1] += f.y;
      }
    }
  }
  for (; j < je; ++j) {
    float4 a = p2[csr[row + j] * 2 + c8];
    const __half2* h = (const __half2*)&a;
#pragma unroll
    for (int m = 0; m < 4; ++m) {
      float2 f = __half22float2(h[m]);
      acc[2 * m] += f.x;
      acc[2 * m + 1] += f.y;
    }
  }
  // combine the two deg-halves (lanes t and t^2 are in the same wave)
#pragma unroll
  for (int m = 0; m < 8; ++m) acc[m] += __shfl_xor(acc[m], 2);
  if (dh == 0) {
    float inv = 1.0f / fmaxf((float)deg, 1.0f);
    float4 q0 = q2[n * 4 + c8 * 2];
    float4 q1v = q2[n * 4 + c8 * 2 + 1];
    float4 o0 = {acc[0] * inv + q0.x, acc[1] * inv + q0.y,
                 acc[2] * inv + q0.z, acc[3] * inv + q0.w};
    float4 o1 = {acc[4] * inv + q1v.x, acc[5] * inv + q1v.y,
                 acc[6] * inv + q1v.z, acc[7] * inv + q1v.w};
    out[n * 4 + c8 * 2] = o0;
    out[n * 4 + c8 * 2 + 1] = o1;
  }
}

extern "C" void kernel_launch(void* const* d_in, const int* in_sizes, int n_in,
                              void* d_out, int out_size, void* d_ws, size_t ws_size,
                              hipStream_t stream) {
  const float* x   = (const float*)d_in[0];
  const int* edge  = (const int*)d_in[1];
  const int* src   = edge;            // edge_index[0]
  const int* dst   = edge + N_EDGES;  // edge_index[1]
  const float* W1l = (const float*)d_in[2];
  const float* b1  = (const float*)d_in[3];
  const float* W1r = (const float*)d_in[4];
  const float* W2l = (const float*)d_in[5];
  const float* b2  = (const float*)d_in[6];
  const float* W2r = (const float*)d_in[7];
  float* out = (float*)d_out;

  // workspace layout (4-byte units; fp16 bases 16B aligned)
  int* gcnt     = (int*)d_ws;          // NBKT*GSTR = 12512 (pad to 12544)
  int* rowstart = gcnt + 12544;        // 100000
  int* cnt      = rowstart + N_NODES;  // 100000
  int* binned   = cnt + N_NODES;       // NBKT*CAP = 2001920
  int* csr      = binned + NBKT * CAP; // 2001920
  __half* p1    = (__half*)(csr + NBKT * CAP);  // 6.4M halves (12.8 MB)
  __half* q1    = p1 + (size_t)N_NODES * 64;    // 6.4M halves (12.8 MB)
  __half* p2    = q1 + (size_t)N_NODES * 64;    // 1.6M halves (3.2 MB)
  float* q2     = (float*)(p2 + (size_t)N_NODES * 16);  // 1.6M floats (6.4 MB)

  hipMemsetAsync(gcnt, 0, NBKT * GSTR * sizeof(int), stream);

  // 1: bin ∪ gemm1 (independent, one dispatch; bin blocks first)
  k_merged1<<<GB + G1B, 256, 0, stream>>>(src, dst, gcnt, binned,
                                          x, W1l, W1r, b1, p1, q1);
  // 2: finalize ∪ fuse1 ∪ gemm2 (256-node bucket per block, 1024 thr)
  k_fuse1c<<<NBKT, 1024, 0, stream>>>((const float4*)p1, gcnt, binned,
                                      W2l, W2r, b2, (const float4*)q1,
                                      csr, rowstart, cnt, p2, q2);
  // 3: fuse2 (4 thr/node, 64 nodes/block)
  k_fuse2<<<(N_NODES + 63) / 64, 256, 0, stream>>>((const float4*)p2,
                                                   (const float4*)q2,
                                                   rowstart, cnt, csr,
                                                   (float4*)out);
}